// Round 1
// baseline (22750.177 us; speedup 1.0000x reference)
//
#include <hip/hip_runtime.h>

#define TT 800

typedef __attribute__((ext_vector_type(8))) short bf16x8;
typedef __attribute__((ext_vector_type(4))) float f32x4;
typedef unsigned short u16;
typedef unsigned int u32;
typedef unsigned long long u64;

constexpr size_t WL0_OFF  = 0;              // [2048][640] bf16 = 2,621,440
constexpr size_t WL1_OFF  = 2621440;        // [2048][1024] bf16 = 4,194,304
constexpr size_t WLIN_OFF = 6815744;        // [128][512] bf16 = 131,072
constexpr size_t H0_OFF   = 6946816;        // [2][256][512] bf16 = 524,288
constexpr size_t H1_OFF   = 7471104;        // [2][256][512] bf16 = 524,288
constexpr size_t BAR_OFF  = 7995392;        // 4 tiles * 128B
constexpr int HB = 256 * 512;               // elements per h buffer

__device__ __forceinline__ u16 f2b(float x) {
  u32 u = __float_as_uint(x);
  return (u16)((u + 0x7FFFu + ((u >> 16) & 1u)) >> 16);   // RNE fp32->bf16
}
__device__ __forceinline__ float sigf(float x) { return 1.f / (1.f + __expf(-x)); }
__device__ __forceinline__ float tanh_f(float x) { float e = __expf(2.f * x); return 1.f - 2.f / (e + 1.f); }

// Pack weights to bf16 with concatenated K layouts.
__global__ void prep_kernel(const float* __restrict__ wih0, const float* __restrict__ whh0,
                            const float* __restrict__ wih1, const float* __restrict__ whh1,
                            const float* __restrict__ wlinf,
                            u16* __restrict__ wl0, u16* __restrict__ wl1, u16* __restrict__ wlin) {
  int i = blockIdx.x * 256 + threadIdx.x;
  const int N0 = 2048 * 640, N1 = 2048 * 1024, N2 = 128 * 512;
  if (i < N0) {
    int col = i / 640, k = i - col * 640;
    float v = (k < 512) ? whh0[col * 512 + k] : wih0[col * 128 + (k - 512)];
    wl0[i] = f2b(v);
  } else if (i < N0 + N1) {
    int j = i - N0, col = j >> 10, k = j & 1023;
    float v = (k < 512) ? wih1[col * 512 + k] : whh1[col * 512 + (k - 512)];
    wl1[j] = f2b(v);
  } else if (i < N0 + N1 + N2) {
    int j = i - N0 - N1, col = j >> 9, k = j & 511;
    wlin[j] = f2b(wlinf[col * 512 + k]);
  }
}

// Per-tile barrier: release fence -> atomic add -> spin -> acquire fence.
__device__ __forceinline__ void tile_barrier(u32* bar, u32 target) {
  __syncthreads();                       // drains vmcnt per wave (stores in L2)
  if (threadIdx.x == 0) {
    __threadfence();                     // release: L2 -> LIC (cross-XCD visibility)
    __hip_atomic_fetch_add(bar, 1u, __ATOMIC_RELAXED, __HIP_MEMORY_SCOPE_AGENT);
    while (__hip_atomic_load(bar, __ATOMIC_RELAXED, __HIP_MEMORY_SCOPE_AGENT) < target)
      __builtin_amdgcn_s_sleep(2);
    __threadfence();                     // acquire: invalidate stale L1/L2
  }
  __syncthreads();
}

// 100 persistent WGs: tile = wg/25 (64 batch rows), role = wg%25:
//   role 0..7  : layer0, 64 hidden units each, K=640 (h0_prev | onehot(z))
//   role 8..23 : layer1, 32 hidden units each, K=1024 (h0_prev | h1_prev)
//   role 24    : logits + online NLL accumulation
// Tick tau: L0 does step tau, L1 does step tau-1, logits does step tau-2. One barrier per tick.
__global__ __launch_bounds__(256, 1) void lstm_kernel(
    const float* __restrict__ bih0, const float* __restrict__ bhh0,
    const float* __restrict__ bih1, const float* __restrict__ bhh1,
    const float* __restrict__ blin,
    const int* __restrict__ z, const int* __restrict__ nfr,
    const u16* __restrict__ wl0, const u16* __restrict__ wl1, const u16* __restrict__ wlin,
    u16* __restrict__ h0buf, u16* __restrict__ h1buf,
    u32* __restrict__ bars, float* __restrict__ out) {
  extern __shared__ char smem[];
  u16* A = (u16*)smem;
  const int wg = blockIdx.x;
  const int tile = wg / 25;
  const int role = wg - tile * 25;
  const int tid = threadIdx.x;
  const int lane = tid & 63;
  const int wv = tid >> 6;
  const int l15 = lane & 15;
  const int l4 = lane >> 4;
  const int row0 = tile * 64;
  u32* bar = bars + tile * 32;
  u32 phase = 0;
  const f32x4 VZ = {0.f, 0.f, 0.f, 0.f};

  // init: zero h0buf[1] and h1buf[1] tile slices (read at tau=0 / tau=1)
  {
    int idx = role * 256 + tid;
    for (int i = idx; i < 16384; i += 6400) {
      u16* base = (i < 8192 ? h0buf : h1buf) + HB + row0 * 512;
      ((u64*)base)[i & 8191] = 0ull;
    }
  }

  float c0s[16], c1s[8], accN[4];
  float bias0[4], bias1[4], biasL[8];
  const u16 *bp0[4], *bp1[4], *bpL[8];
  int U = 0, rh = 0;
#pragma unroll
  for (int i = 0; i < 16; ++i) c0s[i] = 0.f;
#pragma unroll
  for (int i = 0; i < 8; ++i) c1s[i] = 0.f;
  accN[0] = accN[1] = accN[2] = accN[3] = 0.f;

  if (role < 8) {
    U = role * 64 + wv * 16;
#pragma unroll
    for (int g = 0; g < 4; ++g) {
      int col = g * 512 + U + l15;
      bias0[g] = bih0[col] + bhh0[col];
      bp0[g] = wl0 + (size_t)col * 640 + l4 * 8;
    }
  } else if (role < 24) {
    rh = wv >> 1;
    U = (role - 8) * 32 + (wv & 1) * 16;
#pragma unroll
    for (int g = 0; g < 4; ++g) {
      int col = g * 512 + U + l15;
      bias1[g] = bih1[col] + bhh1[col];
      bp1[g] = wl1 + (size_t)col * 1024 + l4 * 8;
    }
  } else {
#pragma unroll
    for (int cb = 0; cb < 8; ++cb) {
      int col = cb * 16 + l15;
      biasL[cb] = blin[col];
      bpL[cb] = wlin + (size_t)col * 512 + l4 * 8;
    }
    if (tid < 64) ((int*)(smem + 33024))[tid] = nfr[row0 + tid];
  }

  tile_barrier(bar, 25u * (++phase));

#pragma unroll 1
  for (int tau = 0; tau <= TT + 1; ++tau) {
    if (role < 8) {
      // ---------------- layer 0, step tau ----------------
      if (tau < TT) {
        const u16* h0p = h0buf + ((tau + 1) & 1) * HB + row0 * 512;
        u16* h0w = h0buf + (tau & 1) * HB + row0 * 512;
        bf16x8 bq[3][4];
#pragma unroll
        for (int p = 0; p < 3; ++p)
#pragma unroll
          for (int g = 0; g < 4; ++g) bq[p][g] = *(const bf16x8*)(bp0[g] + p * 32);
        f32x4 acc[4][4];
#pragma unroll
        for (int r = 0; r < 4; ++r) { acc[r][0] = VZ; acc[r][1] = VZ; acc[r][2] = VZ; acc[r][3] = VZ; }
        int aoff[4], arx[4];
#pragma unroll
        for (int r = 0; r < 4; ++r) { int row = r * 16 + l15; aoff[r] = row * 256; arx[r] = (row & 7) * 8; }

        // pass0: k 0..255
#pragma unroll
        for (int it = 0; it < 8; ++it) {
          int i = it * 256 + tid, r = i >> 5, kc = i & 31;
          *(bf16x8*)(A + r * 256 + ((kc ^ (r & 7)) * 8)) = *(const bf16x8*)(h0p + r * 512 + kc * 8);
        }
        __syncthreads();
        {
          bf16x8 afc[4], afn[4];
#pragma unroll
          for (int r = 0; r < 4; ++r) afc[r] = *(const bf16x8*)(A + aoff[r] + ((l4 * 8) ^ arx[r]));
#pragma unroll
          for (int kb = 0; kb < 8; ++kb) {
            if (kb < 7) {
#pragma unroll
              for (int r = 0; r < 4; ++r) afn[r] = *(const bf16x8*)(A + aoff[r] + (((kb + 1) * 32 + l4 * 8) ^ arx[r]));
            }
#pragma unroll
            for (int r = 0; r < 4; ++r)
#pragma unroll
              for (int g = 0; g < 4; ++g)
                acc[r][g] = __builtin_amdgcn_mfma_f32_16x16x32_bf16(afc[r], bq[kb % 3][g], acc[r][g], 0, 0, 0);
            if (kb + 3 < 20) {
#pragma unroll
              for (int g = 0; g < 4; ++g) bq[kb % 3][g] = *(const bf16x8*)(bp0[g] + (kb + 3) * 32);
            }
            if (kb < 7) {
#pragma unroll
              for (int r = 0; r < 4; ++r) afc[r] = afn[r];
            }
          }
        }
        __syncthreads();
        // pass1: k 256..511
#pragma unroll
        for (int it = 0; it < 8; ++it) {
          int i = it * 256 + tid, r = i >> 5, kc = i & 31;
          *(bf16x8*)(A + r * 256 + ((kc ^ (r & 7)) * 8)) = *(const bf16x8*)(h0p + r * 512 + 256 + kc * 8);
        }
        __syncthreads();
        {
          bf16x8 afc[4], afn[4];
#pragma unroll
          for (int r = 0; r < 4; ++r) afc[r] = *(const bf16x8*)(A + aoff[r] + ((l4 * 8) ^ arx[r]));
#pragma unroll
          for (int kb = 8; kb < 16; ++kb) {
            if (kb < 15) {
#pragma unroll
              for (int r = 0; r < 4; ++r) afn[r] = *(const bf16x8*)(A + aoff[r] + (((kb - 7) * 32 + l4 * 8) ^ arx[r]));
            }
#pragma unroll
            for (int r = 0; r < 4; ++r)
#pragma unroll
              for (int g = 0; g < 4; ++g)
                acc[r][g] = __builtin_amdgcn_mfma_f32_16x16x32_bf16(afc[r], bq[kb % 3][g], acc[r][g], 0, 0, 0);
            if (kb + 3 < 20) {
#pragma unroll
              for (int g = 0; g < 4; ++g) bq[kb % 3][g] = *(const bf16x8*)(bp0[g] + (kb + 3) * 32);
            }
            if (kb < 15) {
#pragma unroll
              for (int r = 0; r < 4; ++r) afc[r] = afn[r];
            }
          }
        }
        __syncthreads();
        // pass2: onehot(z[:,tau-1]) -> k 512..639 (zeros at tau==0)
#pragma unroll
        for (int it = 0; it < 4; ++it) {
          int i = it * 256 + tid, r = i >> 4, kc = i & 15;
          u64* p = (u64*)(A + r * 256 + ((kc ^ (r & 7)) * 8));
          p[0] = 0ull; p[1] = 0ull;
        }
        __syncthreads();
        if (tau >= 1 && tid < 64) {
          int r = tid;
          int zv = z[(row0 + r) * TT + (tau - 1)];
          A[r * 256 + (((zv >> 3) ^ (r & 7)) * 8) + (zv & 7)] = 0x3F80;  // bf16 1.0
        }
        __syncthreads();
        {
          bf16x8 afc[4], afn[4];
#pragma unroll
          for (int r = 0; r < 4; ++r) afc[r] = *(const bf16x8*)(A + aoff[r] + ((l4 * 8) ^ arx[r]));
#pragma unroll
          for (int kb = 16; kb < 20; ++kb) {
            if (kb < 19) {
#pragma unroll
              for (int r = 0; r < 4; ++r) afn[r] = *(const bf16x8*)(A + aoff[r] + (((kb - 15) * 32 + l4 * 8) ^ arx[r]));
            }
#pragma unroll
            for (int r = 0; r < 4; ++r)
#pragma unroll
              for (int g = 0; g < 4; ++g)
                acc[r][g] = __builtin_amdgcn_mfma_f32_16x16x32_bf16(afc[r], bq[kb % 3][g], acc[r][g], 0, 0, 0);
            if (kb < 19) {
#pragma unroll
              for (int r = 0; r < 4; ++r) afc[r] = afn[r];
            }
          }
        }
        // epilogue: LSTM cell, c in registers, h -> global bf16
#pragma unroll
        for (int rbl = 0; rbl < 4; ++rbl) {
#pragma unroll
          for (int q = 0; q < 4; ++q) {
            float iv = acc[rbl][0][q] + bias0[0];
            float fv = acc[rbl][1][q] + bias0[1];
            float gv = acc[rbl][2][q] + bias0[2];
            float ov = acc[rbl][3][q] + bias0[3];
            float cn = sigf(fv) * c0s[rbl * 4 + q] + sigf(iv) * tanh_f(gv);
            float hn = sigf(ov) * tanh_f(cn);
            c0s[rbl * 4 + q] = cn;
            int b = rbl * 16 + l4 * 4 + q;
            h0w[b * 512 + U + l15] = f2b(hn);
          }
        }
      }
    } else if (role < 24) {
      // ---------------- layer 1, step tau-1 ----------------
      if (tau >= 1 && tau <= TT) {
        const u16* h0p = h0buf + ((tau + 1) & 1) * HB + row0 * 512;
        const u16* h1p = h1buf + (tau & 1) * HB + row0 * 512;
        u16* h1w = h1buf + ((tau + 1) & 1) * HB + row0 * 512;
        bf16x8 bq[4][4];
#pragma unroll
        for (int p = 0; p < 4; ++p)
#pragma unroll
          for (int g = 0; g < 4; ++g) bq[p][g] = *(const bf16x8*)(bp1[g] + p * 32);
        f32x4 acc[2][4];
#pragma unroll
        for (int r = 0; r < 2; ++r) { acc[r][0] = VZ; acc[r][1] = VZ; acc[r][2] = VZ; acc[r][3] = VZ; }
        int aoff[2], arx[2];
#pragma unroll
        for (int r = 0; r < 2; ++r) { int row = rh * 32 + r * 16 + l15; aoff[r] = row * 512; arx[r] = (row & 7) * 8; }

        // pass0: h0_prev (k 0..511)
#pragma unroll
        for (int it = 0; it < 16; ++it) {
          int i = it * 256 + tid, r = i >> 6, kc = i & 63;
          *(bf16x8*)(A + r * 512 + ((kc ^ (r & 7)) * 8)) = *(const bf16x8*)(h0p + r * 512 + kc * 8);
        }
        __syncthreads();
        {
          bf16x8 afc[2], afn[2];
#pragma unroll
          for (int r = 0; r < 2; ++r) afc[r] = *(const bf16x8*)(A + aoff[r] + ((l4 * 8) ^ arx[r]));
#pragma unroll
          for (int kb = 0; kb < 16; ++kb) {
            if (kb < 15) {
#pragma unroll
              for (int r = 0; r < 2; ++r) afn[r] = *(const bf16x8*)(A + aoff[r] + (((kb + 1) * 32 + l4 * 8) ^ arx[r]));
            }
#pragma unroll
            for (int r = 0; r < 2; ++r)
#pragma unroll
              for (int g = 0; g < 4; ++g)
                acc[r][g] = __builtin_amdgcn_mfma_f32_16x16x32_bf16(afc[r], bq[kb % 4][g], acc[r][g], 0, 0, 0);
            if (kb + 4 < 32) {
#pragma unroll
              for (int g = 0; g < 4; ++g) bq[kb % 4][g] = *(const bf16x8*)(bp1[g] + (kb + 4) * 32);
            }
            if (kb < 15) {
#pragma unroll
              for (int r = 0; r < 2; ++r) afc[r] = afn[r];
            }
          }
        }
        __syncthreads();
        // pass1: h1_prev (k 512..1023)
#pragma unroll
        for (int it = 0; it < 16; ++it) {
          int i = it * 256 + tid, r = i >> 6, kc = i & 63;
          *(bf16x8*)(A + r * 512 + ((kc ^ (r & 7)) * 8)) = *(const bf16x8*)(h1p + r * 512 + kc * 8);
        }
        __syncthreads();
        {
          bf16x8 afc[2], afn[2];
#pragma unroll
          for (int r = 0; r < 2; ++r) afc[r] = *(const bf16x8*)(A + aoff[r] + ((l4 * 8) ^ arx[r]));
#pragma unroll
          for (int kb = 16; kb < 32; ++kb) {
            if (kb < 31) {
#pragma unroll
              for (int r = 0; r < 2; ++r) afn[r] = *(const bf16x8*)(A + aoff[r] + (((kb - 15) * 32 + l4 * 8) ^ arx[r]));
            }
#pragma unroll
            for (int r = 0; r < 2; ++r)
#pragma unroll
              for (int g = 0; g < 4; ++g)
                acc[r][g] = __builtin_amdgcn_mfma_f32_16x16x32_bf16(afc[r], bq[kb % 4][g], acc[r][g], 0, 0, 0);
            if (kb + 4 < 32) {
#pragma unroll
              for (int g = 0; g < 4; ++g) bq[kb % 4][g] = *(const bf16x8*)(bp1[g] + (kb + 4) * 32);
            }
            if (kb < 31) {
#pragma unroll
              for (int r = 0; r < 2; ++r) afc[r] = afn[r];
            }
          }
        }
#pragma unroll
        for (int rbl = 0; rbl < 2; ++rbl) {
#pragma unroll
          for (int q = 0; q < 4; ++q) {
            float iv = acc[rbl][0][q] + bias1[0];
            float fv = acc[rbl][1][q] + bias1[1];
            float gv = acc[rbl][2][q] + bias1[2];
            float ov = acc[rbl][3][q] + bias1[3];
            float cn = sigf(fv) * c1s[rbl * 4 + q] + sigf(iv) * tanh_f(gv);
            float hn = sigf(ov) * tanh_f(cn);
            c1s[rbl * 4 + q] = cn;
            int b = rh * 32 + rbl * 16 + l4 * 4 + q;
            h1w[b * 512 + U + l15] = f2b(hn);
          }
        }
      }
    } else {
      // ---------------- logits + NLL, step tau-2 ----------------
      if (tau >= 2) {
        const int t2 = tau - 2;
        const u16* h1p = h1buf + (tau & 1) * HB + row0 * 512;
        int* zl = (int*)(smem + 32768);
        int* nfl = (int*)(smem + 33024);
        if (tid < 64) zl[tid] = z[(row0 + tid) * TT + t2];
        bf16x8 bq[3][8];
#pragma unroll
        for (int p = 0; p < 3; ++p)
#pragma unroll
          for (int cb = 0; cb < 8; ++cb) bq[p][cb] = *(const bf16x8*)(bpL[cb] + p * 32);
        f32x4 acc[8];
#pragma unroll
        for (int cb = 0; cb < 8; ++cb) acc[cb] = VZ;
        const int row = wv * 16 + l15;
        const int aoff = row * 256, arx = (row & 7) * 8;

        // pass0: k 0..255
#pragma unroll
        for (int it = 0; it < 8; ++it) {
          int i = it * 256 + tid, r = i >> 5, kc = i & 31;
          *(bf16x8*)(A + r * 256 + ((kc ^ (r & 7)) * 8)) = *(const bf16x8*)(h1p + r * 512 + kc * 8);
        }
        __syncthreads();
        {
          bf16x8 afc = *(const bf16x8*)(A + aoff + ((l4 * 8) ^ arx)), afn;
#pragma unroll
          for (int kb = 0; kb < 8; ++kb) {
            if (kb < 7) afn = *(const bf16x8*)(A + aoff + (((kb + 1) * 32 + l4 * 8) ^ arx));
#pragma unroll
            for (int cb = 0; cb < 8; ++cb)
              acc[cb] = __builtin_amdgcn_mfma_f32_16x16x32_bf16(afc, bq[kb % 3][cb], acc[cb], 0, 0, 0);
            if (kb + 3 < 16) {
#pragma unroll
              for (int cb = 0; cb < 8; ++cb) bq[kb % 3][cb] = *(const bf16x8*)(bpL[cb] + (kb + 3) * 32);
            }
            if (kb < 7) afc = afn;
          }
        }
        __syncthreads();
        // pass1: k 256..511
#pragma unroll
        for (int it = 0; it < 8; ++it) {
          int i = it * 256 + tid, r = i >> 5, kc = i & 31;
          *(bf16x8*)(A + r * 256 + ((kc ^ (r & 7)) * 8)) = *(const bf16x8*)(h1p + r * 512 + 256 + kc * 8);
        }
        __syncthreads();
        {
          bf16x8 afc = *(const bf16x8*)(A + aoff + ((l4 * 8) ^ arx)), afn;
#pragma unroll
          for (int kb = 8; kb < 16; ++kb) {
            if (kb < 15) afn = *(const bf16x8*)(A + aoff + (((kb - 7) * 32 + l4 * 8) ^ arx));
#pragma unroll
            for (int cb = 0; cb < 8; ++cb)
              acc[cb] = __builtin_amdgcn_mfma_f32_16x16x32_bf16(afc, bq[kb % 3][cb], acc[cb], 0, 0, 0);
            if (kb + 3 < 16) {
#pragma unroll
              for (int cb = 0; cb < 8; ++cb) bq[kb % 3][cb] = *(const bf16x8*)(bpL[cb] + (kb + 3) * 32);
            }
            if (kb < 15) afc = afn;
          }
        }
        // online log-softmax + NLL per row (in-wave butterfly over the 16-lane row group)
#pragma unroll
        for (int q = 0; q < 4; ++q) {
          int r = wv * 16 + l4 * 4 + q;
          float v[8];
#pragma unroll
          for (int cb = 0; cb < 8; ++cb) v[cb] = acc[cb][q] + biasL[cb];
          float m = v[0];
#pragma unroll
          for (int cb = 1; cb < 8; ++cb) m = fmaxf(m, v[cb]);
          m = fmaxf(m, __shfl_xor(m, 1, 64));
          m = fmaxf(m, __shfl_xor(m, 2, 64));
          m = fmaxf(m, __shfl_xor(m, 4, 64));
          m = fmaxf(m, __shfl_xor(m, 8, 64));
          float s = 0.f;
#pragma unroll
          for (int cb = 0; cb < 8; ++cb) s += __expf(v[cb] - m);
          s += __shfl_xor(s, 1, 64);
          s += __shfl_xor(s, 2, 64);
          s += __shfl_xor(s, 4, 64);
          s += __shfl_xor(s, 8, 64);
          int zt = zl[r];
          float tv = 0.f;
#pragma unroll
          for (int cb = 0; cb < 8; ++cb)
            tv += ((zt >> 4) == cb && (zt & 15) == l15) ? v[cb] : 0.f;
          tv += __shfl_xor(tv, 1, 64);
          tv += __shfl_xor(tv, 2, 64);
          tv += __shfl_xor(tv, 4, 64);
          tv += __shfl_xor(tv, 8, 64);
          float nll = m + __logf(s) - tv;
          if (t2 < nfl[r]) accN[q] += nll;
        }
      }
    }
    tile_barrier(bar, 25u * (++phase));
  }

  if (role == 24 && l15 == 0) {
#pragma unroll
    for (int q = 0; q < 4; ++q) {
      int r = wv * 16 + l4 * 4 + q;
      out[row0 + r] = accN[q] * (1.0f / TT);
    }
  }
}

extern "C" void kernel_launch(void* const* d_in, const int* in_sizes, int n_in,
                              void* d_out, int out_size, void* d_ws, size_t ws_size,
                              hipStream_t stream) {
  const float* wih0 = (const float*)d_in[0];
  const float* whh0 = (const float*)d_in[1];
  const float* bih0 = (const float*)d_in[2];
  const float* bhh0 = (const float*)d_in[3];
  const float* wih1 = (const float*)d_in[4];
  const float* whh1 = (const float*)d_in[5];
  const float* bih1 = (const float*)d_in[6];
  const float* bhh1 = (const float*)d_in[7];
  const float* wlinf = (const float*)d_in[8];
  const float* blin = (const float*)d_in[9];
  const int* z = (const int*)d_in[10];
  const int* nfr = (const int*)d_in[11];
  float* out = (float*)d_out;
  char* ws = (char*)d_ws;
  u16* wl0 = (u16*)(ws + WL0_OFF);
  u16* wl1 = (u16*)(ws + WL1_OFF);
  u16* wlin = (u16*)(ws + WLIN_OFF);
  u16* h0buf = (u16*)(ws + H0_OFF);
  u16* h1buf = (u16*)(ws + H1_OFF);
  u32* bars = (u32*)(ws + BAR_OFF);

  hipMemsetAsync(ws + BAR_OFF, 0, 512, stream);
  const int NTOT = 2048 * 640 + 2048 * 1024 + 128 * 512;
  prep_kernel<<<dim3((NTOT + 255) / 256), dim3(256), 0, stream>>>(
      wih0, whh0, wih1, whh1, wlinf, wl0, wl1, wlin);
  lstm_kernel<<<dim3(100), dim3(256), 65536, stream>>>(
      bih0, bhh0, bih1, bhh1, blin, z, nfr, wl0, wl1, wlin, h0buf, h1buf, bars, out);
}

// Round 2
// 20267.062 us; speedup vs baseline: 1.1225x; 1.1225x over previous
//
#include <hip/hip_runtime.h>

#define TT 800

typedef __attribute__((ext_vector_type(8))) short bf16x8;
typedef __attribute__((ext_vector_type(4))) float f32x4;
typedef unsigned short u16;
typedef unsigned int u32;
typedef unsigned long long u64;

constexpr size_t WL0_OFF  = 0;              // [2048][640] bf16 = 2,621,440
constexpr size_t WL1_OFF  = 2621440;        // [2048][1024] bf16 = 4,194,304
constexpr size_t WLIN_OFF = 6815744;        // [128][512] bf16 = 131,072
constexpr size_t H0_OFF   = 6946816;        // [2][256][512] bf16 = 524,288
constexpr size_t H1_OFF   = 7471104;        // [2][256][512] bf16 = 524,288
constexpr size_t BAR_OFF  = 7995392;        // 4 tiles * 128B
constexpr int HB = 256 * 512;               // elements per h buffer

__device__ __forceinline__ u16 f2b(float x) {
  u32 u = __float_as_uint(x);
  return (u16)((u + 0x7FFFu + ((u >> 16) & 1u)) >> 16);   // RNE fp32->bf16
}
__device__ __forceinline__ float sigf(float x) { return 1.f / (1.f + __expf(-x)); }
__device__ __forceinline__ float tanh_f(float x) { float e = __expf(2.f * x); return 1.f - 2.f / (e + 1.f); }

// Coherent (cross-XCD) 16B load of h-state: two 8B agent-scope relaxed atomic
// loads -> global_load_dwordx2 sc0 sc1 (bypass L1/L2, served at coherence
// point). This is what lets the WEIGHT loads stay plain/cached: no fences, no
// buffer_inv, L2 stays warm with weights across all 800 ticks.
__device__ __forceinline__ bf16x8 ld_coh16(const u16* p) {
  union { bf16x8 v; u64 q[2]; } u;
  u.q[0] = __hip_atomic_load((const u64*)p,     __ATOMIC_RELAXED, __HIP_MEMORY_SCOPE_AGENT);
  u.q[1] = __hip_atomic_load((const u64*)p + 1, __ATOMIC_RELAXED, __HIP_MEMORY_SCOPE_AGENT);
  return u.v;
}
__device__ __forceinline__ void st_coh16b(u16* p, u16 v) {
  __hip_atomic_store(p, v, __ATOMIC_RELAXED, __HIP_MEMORY_SCOPE_AGENT);
}

// Pack weights to bf16 with concatenated K layouts.
__global__ void prep_kernel(const float* __restrict__ wih0, const float* __restrict__ whh0,
                            const float* __restrict__ wih1, const float* __restrict__ whh1,
                            const float* __restrict__ wlinf,
                            u16* __restrict__ wl0, u16* __restrict__ wl1, u16* __restrict__ wlin) {
  int i = blockIdx.x * 256 + threadIdx.x;
  const int N0 = 2048 * 640, N1 = 2048 * 1024, N2 = 128 * 512;
  if (i < N0) {
    int col = i / 640, k = i - col * 640;
    float v = (k < 512) ? whh0[col * 512 + k] : wih0[col * 128 + (k - 512)];
    wl0[i] = f2b(v);
  } else if (i < N0 + N1) {
    int j = i - N0, col = j >> 10, k = j & 1023;
    float v = (k < 512) ? wih1[col * 512 + k] : whh1[col * 512 + (k - 512)];
    wl1[j] = f2b(v);
  } else if (i < N0 + N1 + N2) {
    int j = i - N0 - N1, col = j >> 9, k = j & 511;
    wlin[j] = f2b(wlinf[col * 512 + k]);
  }
}

// Per-tile barrier, NO fences: h-exchange stores are write-through (sc1), so
// __syncthreads()'s vmcnt(0) drain already makes them globally visible before
// the relaxed atomic add. Consumers read h with coherent loads (forced L2
// miss), so no invalidate is needed on the acquire side.
__device__ __forceinline__ void tile_barrier(u32* bar, u32 target) {
  __syncthreads();                       // drains vmcnt(0): sc1 stores visible device-wide
  if (threadIdx.x == 0) {
    __hip_atomic_fetch_add(bar, 1u, __ATOMIC_RELAXED, __HIP_MEMORY_SCOPE_AGENT);
    while (__hip_atomic_load(bar, __ATOMIC_RELAXED, __HIP_MEMORY_SCOPE_AGENT) < target)
      __builtin_amdgcn_s_sleep(2);
  }
  __syncthreads();
}

// 100 persistent WGs: tile = wg/25 (64 batch rows), role = wg%25:
//   role 0..7  : layer0, 64 hidden units each, K=640 (h0_prev | onehot(z))
//   role 8..23 : layer1, 32 hidden units each, K=1024 (h0_prev | h1_prev)
//   role 24    : logits + online NLL accumulation
// Tick tau: L0 does step tau, L1 does step tau-1, logits does step tau-2. One barrier per tick.
__global__ __launch_bounds__(256, 1) void lstm_kernel(
    const float* __restrict__ bih0, const float* __restrict__ bhh0,
    const float* __restrict__ bih1, const float* __restrict__ bhh1,
    const float* __restrict__ blin,
    const int* __restrict__ z, const int* __restrict__ nfr,
    const u16* __restrict__ wl0, const u16* __restrict__ wl1, const u16* __restrict__ wlin,
    u16* __restrict__ h0buf, u16* __restrict__ h1buf,
    u32* __restrict__ bars, float* __restrict__ out) {
  extern __shared__ char smem[];
  u16* A = (u16*)smem;
  const int wg = blockIdx.x;
  const int tile = wg / 25;
  const int role = wg - tile * 25;
  const int tid = threadIdx.x;
  const int lane = tid & 63;
  const int wv = tid >> 6;
  const int l15 = lane & 15;
  const int l4 = lane >> 4;
  const int row0 = tile * 64;
  u32* bar = bars + tile * 32;
  u32 phase = 0;
  const f32x4 VZ = {0.f, 0.f, 0.f, 0.f};

  // init: zero h0buf[1] and h1buf[1] tile slices (read at tau=0 / tau=1),
  // via coherent stores so consumers' coherent loads see them.
  {
    int idx = role * 256 + tid;
    for (int i = idx; i < 16384; i += 6400) {
      u16* base = (i < 8192 ? h0buf : h1buf) + HB + row0 * 512;
      __hip_atomic_store((u64*)base + (i & 8191), 0ull, __ATOMIC_RELAXED, __HIP_MEMORY_SCOPE_AGENT);
    }
  }

  float c0s[16], c1s[8], accN[4];
  float bias0[4], bias1[4], biasL[8];
  const u16 *bp0[4], *bp1[4], *bpL[8];
  int U = 0, rh = 0;
#pragma unroll
  for (int i = 0; i < 16; ++i) c0s[i] = 0.f;
#pragma unroll
  for (int i = 0; i < 8; ++i) c1s[i] = 0.f;
  accN[0] = accN[1] = accN[2] = accN[3] = 0.f;

  if (role < 8) {
    U = role * 64 + wv * 16;
#pragma unroll
    for (int g = 0; g < 4; ++g) {
      int col = g * 512 + U + l15;
      bias0[g] = bih0[col] + bhh0[col];
      bp0[g] = wl0 + (size_t)col * 640 + l4 * 8;
    }
  } else if (role < 24) {
    rh = wv >> 1;
    U = (role - 8) * 32 + (wv & 1) * 16;
#pragma unroll
    for (int g = 0; g < 4; ++g) {
      int col = g * 512 + U + l15;
      bias1[g] = bih1[col] + bhh1[col];
      bp1[g] = wl1 + (size_t)col * 1024 + l4 * 8;
    }
  } else {
#pragma unroll
    for (int cb = 0; cb < 8; ++cb) {
      int col = cb * 16 + l15;
      biasL[cb] = blin[col];
      bpL[cb] = wlin + (size_t)col * 512 + l4 * 8;
    }
    if (tid < 64) ((int*)(smem + 33024))[tid] = nfr[row0 + tid];
  }

  tile_barrier(bar, 25u * (++phase));

#pragma unroll 1
  for (int tau = 0; tau <= TT + 1; ++tau) {
    if (role < 8) {
      // ---------------- layer 0, step tau ----------------
      if (tau < TT) {
        const u16* h0p = h0buf + ((tau + 1) & 1) * HB + row0 * 512;
        u16* h0w = h0buf + (tau & 1) * HB + row0 * 512;
        bf16x8 bq[3][4];
#pragma unroll
        for (int p = 0; p < 3; ++p)
#pragma unroll
          for (int g = 0; g < 4; ++g) bq[p][g] = *(const bf16x8*)(bp0[g] + p * 32);
        f32x4 acc[4][4];
#pragma unroll
        for (int r = 0; r < 4; ++r) { acc[r][0] = VZ; acc[r][1] = VZ; acc[r][2] = VZ; acc[r][3] = VZ; }
        int aoff[4], arx[4];
#pragma unroll
        for (int r = 0; r < 4; ++r) { int row = r * 16 + l15; aoff[r] = row * 256; arx[r] = (row & 7) * 8; }

        // pass0: k 0..255
#pragma unroll
        for (int it = 0; it < 8; ++it) {
          int i = it * 256 + tid, r = i >> 5, kc = i & 31;
          *(bf16x8*)(A + r * 256 + ((kc ^ (r & 7)) * 8)) = ld_coh16(h0p + r * 512 + kc * 8);
        }
        __syncthreads();
        {
          bf16x8 afc[4], afn[4];
#pragma unroll
          for (int r = 0; r < 4; ++r) afc[r] = *(const bf16x8*)(A + aoff[r] + ((l4 * 8) ^ arx[r]));
#pragma unroll
          for (int kb = 0; kb < 8; ++kb) {
            if (kb < 7) {
#pragma unroll
              for (int r = 0; r < 4; ++r) afn[r] = *(const bf16x8*)(A + aoff[r] + (((kb + 1) * 32 + l4 * 8) ^ arx[r]));
            }
#pragma unroll
            for (int r = 0; r < 4; ++r)
#pragma unroll
              for (int g = 0; g < 4; ++g)
                acc[r][g] = __builtin_amdgcn_mfma_f32_16x16x32_bf16(afc[r], bq[kb % 3][g], acc[r][g], 0, 0, 0);
            if (kb + 3 < 20) {
#pragma unroll
              for (int g = 0; g < 4; ++g) bq[kb % 3][g] = *(const bf16x8*)(bp0[g] + (kb + 3) * 32);
            }
            if (kb < 7) {
#pragma unroll
              for (int r = 0; r < 4; ++r) afc[r] = afn[r];
            }
          }
        }
        __syncthreads();
        // pass1: k 256..511
#pragma unroll
        for (int it = 0; it < 8; ++it) {
          int i = it * 256 + tid, r = i >> 5, kc = i & 31;
          *(bf16x8*)(A + r * 256 + ((kc ^ (r & 7)) * 8)) = ld_coh16(h0p + r * 512 + 256 + kc * 8);
        }
        __syncthreads();
        {
          bf16x8 afc[4], afn[4];
#pragma unroll
          for (int r = 0; r < 4; ++r) afc[r] = *(const bf16x8*)(A + aoff[r] + ((l4 * 8) ^ arx[r]));
#pragma unroll
          for (int kb = 8; kb < 16; ++kb) {
            if (kb < 15) {
#pragma unroll
              for (int r = 0; r < 4; ++r) afn[r] = *(const bf16x8*)(A + aoff[r] + (((kb - 7) * 32 + l4 * 8) ^ arx[r]));
            }
#pragma unroll
            for (int r = 0; r < 4; ++r)
#pragma unroll
              for (int g = 0; g < 4; ++g)
                acc[r][g] = __builtin_amdgcn_mfma_f32_16x16x32_bf16(afc[r], bq[kb % 3][g], acc[r][g], 0, 0, 0);
            if (kb + 3 < 20) {
#pragma unroll
              for (int g = 0; g < 4; ++g) bq[kb % 3][g] = *(const bf16x8*)(bp0[g] + (kb + 3) * 32);
            }
            if (kb < 15) {
#pragma unroll
              for (int r = 0; r < 4; ++r) afc[r] = afn[r];
            }
          }
        }
        __syncthreads();
        // pass2: onehot(z[:,tau-1]) -> k 512..639 (zeros at tau==0)
#pragma unroll
        for (int it = 0; it < 4; ++it) {
          int i = it * 256 + tid, r = i >> 4, kc = i & 15;
          u64* p = (u64*)(A + r * 256 + ((kc ^ (r & 7)) * 8));
          p[0] = 0ull; p[1] = 0ull;
        }
        __syncthreads();
        if (tau >= 1 && tid < 64) {
          int r = tid;
          int zv = z[(row0 + r) * TT + (tau - 1)];
          A[r * 256 + (((zv >> 3) ^ (r & 7)) * 8) + (zv & 7)] = 0x3F80;  // bf16 1.0
        }
        __syncthreads();
        {
          bf16x8 afc[4], afn[4];
#pragma unroll
          for (int r = 0; r < 4; ++r) afc[r] = *(const bf16x8*)(A + aoff[r] + ((l4 * 8) ^ arx[r]));
#pragma unroll
          for (int kb = 16; kb < 20; ++kb) {
            if (kb < 19) {
#pragma unroll
              for (int r = 0; r < 4; ++r) afn[r] = *(const bf16x8*)(A + aoff[r] + (((kb - 15) * 32 + l4 * 8) ^ arx[r]));
            }
#pragma unroll
            for (int r = 0; r < 4; ++r)
#pragma unroll
              for (int g = 0; g < 4; ++g)
                acc[r][g] = __builtin_amdgcn_mfma_f32_16x16x32_bf16(afc[r], bq[kb % 3][g], acc[r][g], 0, 0, 0);
            if (kb < 19) {
#pragma unroll
              for (int r = 0; r < 4; ++r) afc[r] = afn[r];
            }
          }
        }
        // epilogue: LSTM cell, c in registers, h -> global bf16 (coherent stores)
#pragma unroll
        for (int rbl = 0; rbl < 4; ++rbl) {
#pragma unroll
          for (int q = 0; q < 4; ++q) {
            float iv = acc[rbl][0][q] + bias0[0];
            float fv = acc[rbl][1][q] + bias0[1];
            float gv = acc[rbl][2][q] + bias0[2];
            float ov = acc[rbl][3][q] + bias0[3];
            float cn = sigf(fv) * c0s[rbl * 4 + q] + sigf(iv) * tanh_f(gv);
            float hn = sigf(ov) * tanh_f(cn);
            c0s[rbl * 4 + q] = cn;
            int b = rbl * 16 + l4 * 4 + q;
            st_coh16b(&h0w[b * 512 + U + l15], f2b(hn));
          }
        }
      }
    } else if (role < 24) {
      // ---------------- layer 1, step tau-1 ----------------
      if (tau >= 1 && tau <= TT) {
        const u16* h0p = h0buf + ((tau + 1) & 1) * HB + row0 * 512;
        const u16* h1p = h1buf + (tau & 1) * HB + row0 * 512;
        u16* h1w = h1buf + ((tau + 1) & 1) * HB + row0 * 512;
        bf16x8 bq[4][4];
#pragma unroll
        for (int p = 0; p < 4; ++p)
#pragma unroll
          for (int g = 0; g < 4; ++g) bq[p][g] = *(const bf16x8*)(bp1[g] + p * 32);
        f32x4 acc[2][4];
#pragma unroll
        for (int r = 0; r < 2; ++r) { acc[r][0] = VZ; acc[r][1] = VZ; acc[r][2] = VZ; acc[r][3] = VZ; }
        int aoff[2], arx[2];
#pragma unroll
        for (int r = 0; r < 2; ++r) { int row = rh * 32 + r * 16 + l15; aoff[r] = row * 512; arx[r] = (row & 7) * 8; }

        // pass0: h0_prev (k 0..511)
#pragma unroll
        for (int it = 0; it < 16; ++it) {
          int i = it * 256 + tid, r = i >> 6, kc = i & 63;
          *(bf16x8*)(A + r * 512 + ((kc ^ (r & 7)) * 8)) = ld_coh16(h0p + r * 512 + kc * 8);
        }
        __syncthreads();
        {
          bf16x8 afc[2], afn[2];
#pragma unroll
          for (int r = 0; r < 2; ++r) afc[r] = *(const bf16x8*)(A + aoff[r] + ((l4 * 8) ^ arx[r]));
#pragma unroll
          for (int kb = 0; kb < 16; ++kb) {
            if (kb < 15) {
#pragma unroll
              for (int r = 0; r < 2; ++r) afn[r] = *(const bf16x8*)(A + aoff[r] + (((kb + 1) * 32 + l4 * 8) ^ arx[r]));
            }
#pragma unroll
            for (int r = 0; r < 2; ++r)
#pragma unroll
              for (int g = 0; g < 4; ++g)
                acc[r][g] = __builtin_amdgcn_mfma_f32_16x16x32_bf16(afc[r], bq[kb % 4][g], acc[r][g], 0, 0, 0);
            if (kb + 4 < 32) {
#pragma unroll
              for (int g = 0; g < 4; ++g) bq[kb % 4][g] = *(const bf16x8*)(bp1[g] + (kb + 4) * 32);
            }
            if (kb < 15) {
#pragma unroll
              for (int r = 0; r < 2; ++r) afc[r] = afn[r];
            }
          }
        }
        __syncthreads();
        // pass1: h1_prev (k 512..1023)
#pragma unroll
        for (int it = 0; it < 16; ++it) {
          int i = it * 256 + tid, r = i >> 6, kc = i & 63;
          *(bf16x8*)(A + r * 512 + ((kc ^ (r & 7)) * 8)) = ld_coh16(h1p + r * 512 + kc * 8);
        }
        __syncthreads();
        {
          bf16x8 afc[2], afn[2];
#pragma unroll
          for (int r = 0; r < 2; ++r) afc[r] = *(const bf16x8*)(A + aoff[r] + ((l4 * 8) ^ arx[r]));
#pragma unroll
          for (int kb = 16; kb < 32; ++kb) {
            if (kb < 31) {
#pragma unroll
              for (int r = 0; r < 2; ++r) afn[r] = *(const bf16x8*)(A + aoff[r] + (((kb - 15) * 32 + l4 * 8) ^ arx[r]));
            }
#pragma unroll
            for (int r = 0; r < 2; ++r)
#pragma unroll
              for (int g = 0; g < 4; ++g)
                acc[r][g] = __builtin_amdgcn_mfma_f32_16x16x32_bf16(afc[r], bq[kb % 4][g], acc[r][g], 0, 0, 0);
            if (kb + 4 < 32) {
#pragma unroll
              for (int g = 0; g < 4; ++g) bq[kb % 4][g] = *(const bf16x8*)(bp1[g] + (kb + 4) * 32);
            }
            if (kb < 31) {
#pragma unroll
              for (int r = 0; r < 2; ++r) afc[r] = afn[r];
            }
          }
        }
#pragma unroll
        for (int rbl = 0; rbl < 2; ++rbl) {
#pragma unroll
          for (int q = 0; q < 4; ++q) {
            float iv = acc[rbl][0][q] + bias1[0];
            float fv = acc[rbl][1][q] + bias1[1];
            float gv = acc[rbl][2][q] + bias1[2];
            float ov = acc[rbl][3][q] + bias1[3];
            float cn = sigf(fv) * c1s[rbl * 4 + q] + sigf(iv) * tanh_f(gv);
            float hn = sigf(ov) * tanh_f(cn);
            c1s[rbl * 4 + q] = cn;
            int b = rh * 32 + rbl * 16 + l4 * 4 + q;
            st_coh16b(&h1w[b * 512 + U + l15], f2b(hn));
          }
        }
      }
    } else {
      // ---------------- logits + NLL, step tau-2 ----------------
      if (tau >= 2) {
        const int t2 = tau - 2;
        const u16* h1p = h1buf + (tau & 1) * HB + row0 * 512;
        int* zl = (int*)(smem + 32768);
        int* nfl = (int*)(smem + 33024);
        if (tid < 64) zl[tid] = z[(row0 + tid) * TT + t2];
        bf16x8 bq[3][8];
#pragma unroll
        for (int p = 0; p < 3; ++p)
#pragma unroll
          for (int cb = 0; cb < 8; ++cb) bq[p][cb] = *(const bf16x8*)(bpL[cb] + p * 32);
        f32x4 acc[8];
#pragma unroll
        for (int cb = 0; cb < 8; ++cb) acc[cb] = VZ;
        const int row = wv * 16 + l15;
        const int aoff = row * 256, arx = (row & 7) * 8;

        // pass0: k 0..255
#pragma unroll
        for (int it = 0; it < 8; ++it) {
          int i = it * 256 + tid, r = i >> 5, kc = i & 31;
          *(bf16x8*)(A + r * 256 + ((kc ^ (r & 7)) * 8)) = ld_coh16(h1p + r * 512 + kc * 8);
        }
        __syncthreads();
        {
          bf16x8 afc = *(const bf16x8*)(A + aoff + ((l4 * 8) ^ arx)), afn;
#pragma unroll
          for (int kb = 0; kb < 8; ++kb) {
            if (kb < 7) afn = *(const bf16x8*)(A + aoff + (((kb + 1) * 32 + l4 * 8) ^ arx));
#pragma unroll
            for (int cb = 0; cb < 8; ++cb)
              acc[cb] = __builtin_amdgcn_mfma_f32_16x16x32_bf16(afc, bq[kb % 3][cb], acc[cb], 0, 0, 0);
            if (kb + 3 < 16) {
#pragma unroll
              for (int cb = 0; cb < 8; ++cb) bq[kb % 3][cb] = *(const bf16x8*)(bpL[cb] + (kb + 3) * 32);
            }
            if (kb < 7) afc = afn;
          }
        }
        __syncthreads();
        // pass1: k 256..511
#pragma unroll
        for (int it = 0; it < 8; ++it) {
          int i = it * 256 + tid, r = i >> 5, kc = i & 31;
          *(bf16x8*)(A + r * 256 + ((kc ^ (r & 7)) * 8)) = ld_coh16(h1p + r * 512 + 256 + kc * 8);
        }
        __syncthreads();
        {
          bf16x8 afc = *(const bf16x8*)(A + aoff + ((l4 * 8) ^ arx)), afn;
#pragma unroll
          for (int kb = 8; kb < 16; ++kb) {
            if (kb < 15) afn = *(const bf16x8*)(A + aoff + (((kb - 7) * 32 + l4 * 8) ^ arx));
#pragma unroll
            for (int cb = 0; cb < 8; ++cb)
              acc[cb] = __builtin_amdgcn_mfma_f32_16x16x32_bf16(afc, bq[kb % 3][cb], acc[cb], 0, 0, 0);
            if (kb + 3 < 16) {
#pragma unroll
              for (int cb = 0; cb < 8; ++cb) bq[kb % 3][cb] = *(const bf16x8*)(bpL[cb] + (kb + 3) * 32);
            }
            if (kb < 15) afc = afn;
          }
        }
        // online log-softmax + NLL per row (in-wave butterfly over the 16-lane row group)
#pragma unroll
        for (int q = 0; q < 4; ++q) {
          int r = wv * 16 + l4 * 4 + q;
          float v[8];
#pragma unroll
          for (int cb = 0; cb < 8; ++cb) v[cb] = acc[cb][q] + biasL[cb];
          float m = v[0];
#pragma unroll
          for (int cb = 1; cb < 8; ++cb) m = fmaxf(m, v[cb]);
          m = fmaxf(m, __shfl_xor(m, 1, 64));
          m = fmaxf(m, __shfl_xor(m, 2, 64));
          m = fmaxf(m, __shfl_xor(m, 4, 64));
          m = fmaxf(m, __shfl_xor(m, 8, 64));
          float s = 0.f;
#pragma unroll
          for (int cb = 0; cb < 8; ++cb) s += __expf(v[cb] - m);
          s += __shfl_xor(s, 1, 64);
          s += __shfl_xor(s, 2, 64);
          s += __shfl_xor(s, 4, 64);
          s += __shfl_xor(s, 8, 64);
          int zt = zl[r];
          float tv = 0.f;
#pragma unroll
          for (int cb = 0; cb < 8; ++cb)
            tv += ((zt >> 4) == cb && (zt & 15) == l15) ? v[cb] : 0.f;
          tv += __shfl_xor(tv, 1, 64);
          tv += __shfl_xor(tv, 2, 64);
          tv += __shfl_xor(tv, 4, 64);
          tv += __shfl_xor(tv, 8, 64);
          float nll = m + __logf(s) - tv;
          if (t2 < nfl[r]) accN[q] += nll;
        }
      }
    }
    tile_barrier(bar, 25u * (++phase));
  }

  if (role == 24 && l15 == 0) {
#pragma unroll
    for (int q = 0; q < 4; ++q) {
      int r = wv * 16 + l4 * 4 + q;
      out[row0 + r] = accN[q] * (1.0f / TT);
    }
  }
}

extern "C" void kernel_launch(void* const* d_in, const int* in_sizes, int n_in,
                              void* d_out, int out_size, void* d_ws, size_t ws_size,
                              hipStream_t stream) {
  const float* wih0 = (const float*)d_in[0];
  const float* whh0 = (const float*)d_in[1];
  const float* bih0 = (const float*)d_in[2];
  const float* bhh0 = (const float*)d_in[3];
  const float* wih1 = (const float*)d_in[4];
  const float* whh1 = (const float*)d_in[5];
  const float* bih1 = (const float*)d_in[6];
  const float* bhh1 = (const float*)d_in[7];
  const float* wlinf = (const float*)d_in[8];
  const float* blin = (const float*)d_in[9];
  const int* z = (const int*)d_in[10];
  const int* nfr = (const int*)d_in[11];
  float* out = (float*)d_out;
  char* ws = (char*)d_ws;
  u16* wl0 = (u16*)(ws + WL0_OFF);
  u16* wl1 = (u16*)(ws + WL1_OFF);
  u16* wlin = (u16*)(ws + WLIN_OFF);
  u16* h0buf = (u16*)(ws + H0_OFF);
  u16* h1buf = (u16*)(ws + H1_OFF);
  u32* bars = (u32*)(ws + BAR_OFF);

  hipMemsetAsync(ws + BAR_OFF, 0, 512, stream);
  const int NTOT = 2048 * 640 + 2048 * 1024 + 128 * 512;
  prep_kernel<<<dim3((NTOT + 255) / 256), dim3(256), 0, stream>>>(
      wih0, whh0, wih1, whh1, wlinf, wl0, wl1, wlin);
  lstm_kernel<<<dim3(100), dim3(256), 65536, stream>>>(
      bih0, bhh0, bih1, bhh1, blin, z, nfr, wl0, wl1, wlin, h0buf, h1buf, bars, out);
}